// Round 1
// baseline (217.857 us; speedup 1.0000x reference)
//
#include <hip/hip_runtime.h>

// TensorizedAutoencoder: B=2048 rows, D=512 in, H=128 hidden, K=16 experts.
// Pipeline: memset counts -> assign kernel (argmin + bucket rows by cluster)
//           -> fused AE kernel (per 16-row tile of one cluster: xc->enc->relu->dec).
// All math f32 (matches reference precision; no fp32 MFMA on CDNA4).

#define BB 2048
#define DD 512
#define HH 128
#define KK 16
#define TM 16
#define MAXT (BB / TM)   // 128 tiles worst case per cluster
#define DPAD (DD + 4)    // +4 floats: keeps 16B alignment, spreads rows over banks
#define HPAD (HH + 4)

__global__ __launch_bounds__(256) void assign_k(const float* __restrict__ x,
                                                const float* __restrict__ c,
                                                int* __restrict__ counts,
                                                int* __restrict__ rows) {
    const int lane = threadIdx.x & 63;
    const int row = (blockIdx.x << 2) + (threadIdx.x >> 6);
    if (row >= BB) return;

    const float4* x4 = reinterpret_cast<const float4*>(x + (size_t)row * DD);
    const float4 xa = x4[lane * 2];
    const float4 xb = x4[lane * 2 + 1];

    float bestd = 3.4e38f;
    int bestk = 0;
    for (int k = 0; k < KK; ++k) {
        const float4* c4 = reinterpret_cast<const float4*>(c + (size_t)k * DD);
        const float4 ca = c4[lane * 2];
        const float4 cb = c4[lane * 2 + 1];
        float dotv = xa.x * ca.x + xa.y * ca.y + xa.z * ca.z + xa.w * ca.w
                   + xb.x * cb.x + xb.y * cb.y + xb.z * cb.z + xb.w * cb.w;
        float cc = ca.x * ca.x + ca.y * ca.y + ca.z * ca.z + ca.w * ca.w
                 + cb.x * cb.x + cb.y * cb.y + cb.z * cb.z + cb.w * cb.w;
        float v = cc - 2.0f * dotv;   // ||x||^2 constant across k: dropped (argmin-invariant)
        #pragma unroll
        for (int off = 32; off > 0; off >>= 1) v += __shfl_xor(v, off, 64);
        if (v < bestd) { bestd = v; bestk = k; }   // strict < keeps first-min (jnp.argmin)
    }
    if (lane == 0) {
        const int pos = atomicAdd(&counts[bestk], 1);
        rows[bestk * BB + pos] = row;
    }
}

__global__ __launch_bounds__(256) void ae_k(const float* __restrict__ x,
                                            const float* __restrict__ c,
                                            const float* __restrict__ encW,
                                            const float* __restrict__ encB,
                                            const float* __restrict__ decW,
                                            const float* __restrict__ decB,
                                            const int* __restrict__ counts,
                                            const int* __restrict__ rows,
                                            float* __restrict__ out) {
    const int k = blockIdx.x >> 7;            // MAXT = 128
    const int tile = blockIdx.x & (MAXT - 1);
    const int cnt = counts[k];
    const int base = tile * TM;
    if (base >= cnt) return;
    const int nrows = min(TM, cnt - base);

    __shared__ float xc_s[TM][DPAD];
    __shared__ float e_s[TM][HPAD];
    __shared__ int rows_s[TM];

    const int tid = threadIdx.x;
    if (tid < TM) rows_s[tid] = (tid < nrows) ? rows[k * BB + base + tid] : 0;
    __syncthreads();

    // ---- stage xc = x[row] - centers[k] into LDS (zero-fill unused rows) ----
    {
        const float4* c4 = reinterpret_cast<const float4*>(c + (size_t)k * DD);
        for (int i = tid; i < TM * (DD / 4); i += 256) {
            const int r = i >> 7;        // DD/4 = 128
            const int d4 = i & 127;
            float4 v = make_float4(0.f, 0.f, 0.f, 0.f);
            if (r < nrows) {
                const float4 xv =
                    reinterpret_cast<const float4*>(x + (size_t)rows_s[r] * DD)[d4];
                const float4 cv = c4[d4];
                v = make_float4(xv.x - cv.x, xv.y - cv.y, xv.z - cv.z, xv.w - cv.w);
            }
            *reinterpret_cast<float4*>(&xc_s[r][d4 * 4]) = v;
        }
    }
    __syncthreads();

    // ---- encoder: e[r][h] = relu(sum_d xc[r][d] * encW[k][d][h] + encB[k][h]) ----
    {
        const int row = tid >> 4;           // 16 rows
        const int h0 = (tid & 15) * 8;      // 16 h-groups x 8
        const float* W = encW + (size_t)k * DD * HH + h0;
        float acc[8] = {0.f, 0.f, 0.f, 0.f, 0.f, 0.f, 0.f, 0.f};
        #pragma unroll 4
        for (int d = 0; d < DD; ++d) {
            const float xv = xc_s[row][d];
            const float4 wa = *reinterpret_cast<const float4*>(W + (size_t)d * HH);
            const float4 wb = *reinterpret_cast<const float4*>(W + (size_t)d * HH + 4);
            acc[0] += xv * wa.x; acc[1] += xv * wa.y;
            acc[2] += xv * wa.z; acc[3] += xv * wa.w;
            acc[4] += xv * wb.x; acc[5] += xv * wb.y;
            acc[6] += xv * wb.z; acc[7] += xv * wb.w;
        }
        const float* eb = encB + k * HH + h0;
        #pragma unroll
        for (int j = 0; j < 8; ++j)
            e_s[row][h0 + j] = fmaxf(acc[j] + eb[j], 0.0f);
    }
    __syncthreads();

    // ---- decoder: out[r][d] = sum_h e[r][h] * decW[k][h][d] + decB[k][d] ----
    {
        const int r2 = tid >> 5;            // 0..7 ; thread owns rows r2 and r2+8
        const int d0 = (tid & 31) * 16;     // 32 d-groups x 16
        const float* V = decW + (size_t)k * HH * DD + d0;
        float acc0[16];
        float acc1[16];
        #pragma unroll
        for (int j = 0; j < 16; ++j) { acc0[j] = 0.f; acc1[j] = 0.f; }

        for (int h = 0; h < HH; ++h) {
            const float e0 = e_s[r2][h];
            const float e1 = e_s[r2 + 8][h];
            const float* Vh = V + (size_t)h * DD;
            #pragma unroll
            for (int j = 0; j < 4; ++j) {
                const float4 w = *reinterpret_cast<const float4*>(Vh + j * 4);
                acc0[j * 4 + 0] += e0 * w.x; acc0[j * 4 + 1] += e0 * w.y;
                acc0[j * 4 + 2] += e0 * w.z; acc0[j * 4 + 3] += e0 * w.w;
                acc1[j * 4 + 0] += e1 * w.x; acc1[j * 4 + 1] += e1 * w.y;
                acc1[j * 4 + 2] += e1 * w.z; acc1[j * 4 + 3] += e1 * w.w;
            }
        }
        const float* db = decB + k * DD + d0;
        if (r2 < nrows) {
            float4* o4 = reinterpret_cast<float4*>(out + (size_t)rows_s[r2] * DD + d0);
            #pragma unroll
            for (int j = 0; j < 4; ++j) {
                o4[j] = make_float4(acc0[j * 4 + 0] + db[j * 4 + 0],
                                    acc0[j * 4 + 1] + db[j * 4 + 1],
                                    acc0[j * 4 + 2] + db[j * 4 + 2],
                                    acc0[j * 4 + 3] + db[j * 4 + 3]);
            }
        }
        if (r2 + 8 < nrows) {
            float4* o4 = reinterpret_cast<float4*>(out + (size_t)rows_s[r2 + 8] * DD + d0);
            #pragma unroll
            for (int j = 0; j < 4; ++j) {
                o4[j] = make_float4(acc1[j * 4 + 0] + db[j * 4 + 0],
                                    acc1[j * 4 + 1] + db[j * 4 + 1],
                                    acc1[j * 4 + 2] + db[j * 4 + 2],
                                    acc1[j * 4 + 3] + db[j * 4 + 3]);
            }
        }
    }
}

extern "C" void kernel_launch(void* const* d_in, const int* in_sizes, int n_in,
                              void* d_out, int out_size, void* d_ws, size_t ws_size,
                              hipStream_t stream) {
    const float* x       = (const float*)d_in[0];
    const float* centers = (const float*)d_in[1];
    const float* enc_W   = (const float*)d_in[2];
    const float* enc_b   = (const float*)d_in[3];
    const float* dec_W   = (const float*)d_in[4];
    const float* dec_b   = (const float*)d_in[5];
    float* out = (float*)d_out;

    // ws layout: [0,64) counts (K ints), [256, 256+K*B*4) row lists
    int* counts = (int*)d_ws;
    int* rows   = (int*)((char*)d_ws + 256);

    hipMemsetAsync(counts, 0, KK * sizeof(int), stream);
    assign_k<<<BB / 4, 256, 0, stream>>>(x, centers, counts, rows);
    ae_k<<<KK * MAXT, 256, 0, stream>>>(x, centers, enc_W, enc_b, dec_W, dec_b,
                                        counts, rows, out);
}

// Round 2
// 163.045 us; speedup vs baseline: 1.3362x; 1.3362x over previous
//
#include <hip/hip_runtime.h>

// TensorizedAutoencoder: B=2048, D=512, H=128, K=16, f32.
// R2: split fused AE into enc_k (tile x 4 h-chunks, 4-way split D-reduction)
//     and dec_k (tile x 4 d-chunks). 512 active blocks per kernel instead of
//     128 -> attacks the 4% occupancy / 2.3% VALUBusy latency starvation.
// e (B x H) round-trips through d_ws. xc recomputed during LDS staging.

#define BB 2048
#define DD 512
#define HH 128
#define KK 16
#define TM 16
#define MAXT (BB / TM)   // 128 tiles worst case per cluster

__global__ __launch_bounds__(256) void assign_k(const float* __restrict__ x,
                                                const float* __restrict__ c,
                                                int* __restrict__ counts,
                                                int* __restrict__ rows) {
    const int lane = threadIdx.x & 63;
    const int row = (blockIdx.x << 2) + (threadIdx.x >> 6);
    if (row >= BB) return;

    const float4* x4 = reinterpret_cast<const float4*>(x + (size_t)row * DD);
    const float4 xa = x4[lane * 2];
    const float4 xb = x4[lane * 2 + 1];

    float bestd = 3.4e38f;
    int bestk = 0;
    #pragma unroll 4
    for (int k = 0; k < KK; ++k) {
        const float4* c4 = reinterpret_cast<const float4*>(c + (size_t)k * DD);
        const float4 ca = c4[lane * 2];
        const float4 cb = c4[lane * 2 + 1];
        float dotv = xa.x * ca.x + xa.y * ca.y + xa.z * ca.z + xa.w * ca.w
                   + xb.x * cb.x + xb.y * cb.y + xb.z * cb.z + xb.w * cb.w;
        float cc = ca.x * ca.x + ca.y * ca.y + ca.z * ca.z + ca.w * ca.w
                 + cb.x * cb.x + cb.y * cb.y + cb.z * cb.z + cb.w * cb.w;
        float v = cc - 2.0f * dotv;   // ||x||^2 constant across k (argmin-invariant)
        #pragma unroll
        for (int off = 32; off > 0; off >>= 1) v += __shfl_xor(v, off, 64);
        if (v < bestd) { bestd = v; bestk = k; }   // strict < keeps first-min
    }
    if (lane == 0) {
        const int pos = atomicAdd(&counts[bestk], 1);
        rows[bestk * BB + pos] = row;
    }
}

// ---- encoder: e[r][h] = relu(sum_d (x[r][d]-c[k][d]) * encW[k][d][h] + encB[k][h])
// grid: (KK*MAXT, 4 h-chunks of 32). Thread layout (dc=tid>>6, r=(tid>>2)&15,
// hg=tid&3): wave-uniform dc keeps xs reads <=2-way bank aliased (free).
__global__ __launch_bounds__(256) void enc_k(const float* __restrict__ x,
                                             const float* __restrict__ c,
                                             const float* __restrict__ encW,
                                             const float* __restrict__ encB,
                                             const int* __restrict__ counts,
                                             const int* __restrict__ rows,
                                             float* __restrict__ e) {
    const int k = blockIdx.x >> 7;
    const int tile = blockIdx.x & (MAXT - 1);
    const int hc = blockIdx.y;            // 0..3
    const int cnt = counts[k];
    const int base = tile * TM;
    if (base >= cnt) return;
    const int nrows = min(TM, cnt - base);

    __shared__ float xs[TM][DD + 4];      // 33 KB, row stride 516 (16B-aligned)
    __shared__ float ps[TM][4][32];       // 8 KB partials
    __shared__ int rs[TM];

    const int tid = threadIdx.x;
    if (tid < TM) rs[tid] = (tid < nrows) ? rows[k * BB + base + tid] : 0;
    __syncthreads();

    {   // stage xc = x[row] - c[k] into LDS (zero-fill unused rows)
        const float4* c4 = reinterpret_cast<const float4*>(c + (size_t)k * DD);
        for (int i = tid; i < TM * (DD / 4); i += 256) {
            const int r = i >> 7, d4 = i & 127;
            float4 v = make_float4(0.f, 0.f, 0.f, 0.f);
            if (r < nrows) {
                const float4 xv =
                    reinterpret_cast<const float4*>(x + (size_t)rs[r] * DD)[d4];
                const float4 cv = c4[d4];
                v = make_float4(xv.x - cv.x, xv.y - cv.y, xv.z - cv.z, xv.w - cv.w);
            }
            *reinterpret_cast<float4*>(&xs[r][d4 * 4]) = v;
        }
    }
    __syncthreads();

    const int dc = tid >> 6;              // 0..3 (wave-uniform)
    const int r  = (tid >> 2) & 15;
    const int hg = tid & 3;
    const int h0 = hc * 32 + hg * 8;
    const float* W = encW + (size_t)k * DD * HH + (size_t)(dc * 128) * HH + h0;

    float acc[8] = {0.f, 0.f, 0.f, 0.f, 0.f, 0.f, 0.f, 0.f};
    #pragma unroll 4
    for (int d = 0; d < 128; ++d) {
        const float xv = xs[r][dc * 128 + d];
        const float4 wa = *reinterpret_cast<const float4*>(W + (size_t)d * HH);
        const float4 wb = *reinterpret_cast<const float4*>(W + (size_t)d * HH + 4);
        acc[0] += xv * wa.x; acc[1] += xv * wa.y;
        acc[2] += xv * wa.z; acc[3] += xv * wa.w;
        acc[4] += xv * wb.x; acc[5] += xv * wb.y;
        acc[6] += xv * wb.z; acc[7] += xv * wb.w;
    }
    #pragma unroll
    for (int j = 0; j < 8; ++j) ps[r][dc][hg * 8 + j] = acc[j];
    __syncthreads();

    // reduce 4 partials, bias+relu, scatter to e[row][h]
    for (int i = tid; i < TM * 32; i += 256) {
        const int rr = i >> 5, hh = i & 31;
        if (rr < nrows) {
            float v = ps[rr][0][hh] + ps[rr][1][hh] + ps[rr][2][hh] + ps[rr][3][hh];
            v = fmaxf(v + encB[k * HH + hc * 32 + hh], 0.0f);
            e[(size_t)rs[rr] * HH + hc * 32 + hh] = v;
        }
    }
}

// ---- decoder: out[r][d] = sum_h e[r][h] * decW[k][h][d] + decB[k][d]
// grid: (KK*MAXT, 4 d-chunks of 128). Thread (r=tid>>4, dg=tid&15): one row,
// 8 consecutive d each; 128-iter h loop; es reads are LDS broadcasts.
__global__ __launch_bounds__(256) void dec_k(const float* __restrict__ e,
                                             const float* __restrict__ decW,
                                             const float* __restrict__ decB,
                                             const int* __restrict__ counts,
                                             const int* __restrict__ rows,
                                             float* __restrict__ out) {
    const int k = blockIdx.x >> 7;
    const int tile = blockIdx.x & (MAXT - 1);
    const int dchunk = blockIdx.y;        // 0..3
    const int cnt = counts[k];
    const int base = tile * TM;
    if (base >= cnt) return;
    const int nrows = min(TM, cnt - base);

    __shared__ float es[TM][HH + 4];      // 8.4 KB, row stride 132
    __shared__ int rs[TM];

    const int tid = threadIdx.x;
    if (tid < TM) rs[tid] = (tid < nrows) ? rows[k * BB + base + tid] : 0;
    __syncthreads();

    for (int i = tid; i < TM * (HH / 4); i += 256) {   // 512 float4, 2/thread
        const int r = i >> 5, h4 = i & 31;
        float4 v = make_float4(0.f, 0.f, 0.f, 0.f);
        if (r < nrows)
            v = reinterpret_cast<const float4*>(e + (size_t)rs[r] * HH)[h4];
        *reinterpret_cast<float4*>(&es[r][h4 * 4]) = v;
    }
    __syncthreads();

    const int r  = tid >> 4;              // 0..15
    const int dg = tid & 15;
    const int d0 = dchunk * 128 + dg * 8;
    const float* V = decW + (size_t)k * HH * DD + d0;

    float acc[8] = {0.f, 0.f, 0.f, 0.f, 0.f, 0.f, 0.f, 0.f};
    #pragma unroll 4
    for (int h = 0; h < HH; ++h) {
        const float ev = es[r][h];
        const float4 wa = *reinterpret_cast<const float4*>(V + (size_t)h * DD);
        const float4 wb = *reinterpret_cast<const float4*>(V + (size_t)h * DD + 4);
        acc[0] += ev * wa.x; acc[1] += ev * wa.y;
        acc[2] += ev * wa.z; acc[3] += ev * wa.w;
        acc[4] += ev * wb.x; acc[5] += ev * wb.y;
        acc[6] += ev * wb.z; acc[7] += ev * wb.w;
    }
    if (r < nrows) {
        const float* db = decB + k * DD + d0;
        float4* o4 = reinterpret_cast<float4*>(out + (size_t)rs[r] * DD + d0);
        o4[0] = make_float4(acc[0] + db[0], acc[1] + db[1],
                            acc[2] + db[2], acc[3] + db[3]);
        o4[1] = make_float4(acc[4] + db[4], acc[5] + db[5],
                            acc[6] + db[6], acc[7] + db[7]);
    }
}

extern "C" void kernel_launch(void* const* d_in, const int* in_sizes, int n_in,
                              void* d_out, int out_size, void* d_ws, size_t ws_size,
                              hipStream_t stream) {
    const float* x       = (const float*)d_in[0];
    const float* centers = (const float*)d_in[1];
    const float* enc_W   = (const float*)d_in[2];
    const float* enc_b   = (const float*)d_in[3];
    const float* dec_W   = (const float*)d_in[4];
    const float* dec_b   = (const float*)d_in[5];
    float* out = (float*)d_out;

    // ws layout: [0,64) counts; [4096, 4096+128K) row lists; then e (B*H f32, 1 MB)
    int*   counts = (int*)d_ws;
    int*   rows   = (int*)((char*)d_ws + 4096);
    float* e      = (float*)((char*)d_ws + 4096 + KK * BB * sizeof(int));

    hipMemsetAsync(counts, 0, KK * sizeof(int), stream);
    assign_k<<<BB / 4, 256, 0, stream>>>(x, centers, counts, rows);
    enc_k<<<dim3(KK * MAXT, 4), 256, 0, stream>>>(x, centers, enc_W, enc_b,
                                                  counts, rows, e);
    dec_k<<<dim3(KK * MAXT, 4), 256, 0, stream>>>(e, dec_W, dec_b,
                                                  counts, rows, out);
}

// Round 3
// 76.700 us; speedup vs baseline: 2.8404x; 2.1258x over previous
//
#include <hip/hip_runtime.h>

// TensorizedAutoencoder: B=2048, D=512, H=128, K=16, f32 in/out.
// R3: MFMA bf16 path. Per 16-row tile: enc = [16x512]@[512x128], dec =
// [16x128]@[128x512] via mfma_f32_16x16x32_bf16. A-operand (xc / e) split
// hi+lo bf16 (2 passes -> A near-exact); B (weights) bf16 RNE (err ~2e-3).
// A staged in LDS pre-fragmented (lane-linear, conflict-free); B fragments
// loaded global->regs (8 f32 scalar loads each, deep ILP hides L2 latency).

#define BB 2048
#define DD 512
#define HH 128
#define KK 16
#define TM 16
#define MAXT (BB / TM)   // 128 tiles worst case per cluster

typedef float f4v __attribute__((ext_vector_type(4)));
typedef short s8v __attribute__((ext_vector_type(8)));

__device__ inline ushort f2bf(float f) {           // f32 -> bf16 RNE
    uint u = __float_as_uint(f);
    return (ushort)((u + 0x7fffu + ((u >> 16) & 1u)) >> 16);
}
__device__ inline float bf2f(ushort h) { return __uint_as_float(((uint)h) << 16); }

__device__ inline s8v pack8(const float b[8]) {
    union { s8v v; ushort u[8]; } p;
#pragma unroll
    for (int j = 0; j < 8; ++j) p.u[j] = f2bf(b[j]);
    return p.v;
}

__global__ __launch_bounds__(256) void assign_k(const float* __restrict__ x,
                                                const float* __restrict__ c,
                                                int* __restrict__ counts,
                                                int* __restrict__ rows) {
    const int lane = threadIdx.x & 63;
    const int row = (blockIdx.x << 2) + (threadIdx.x >> 6);
    if (row >= BB) return;

    const float4* x4 = reinterpret_cast<const float4*>(x + (size_t)row * DD);
    const float4 xa = x4[lane * 2];
    const float4 xb = x4[lane * 2 + 1];

    float bestd = 3.4e38f;
    int bestk = 0;
    for (int k = 0; k < KK; ++k) {
        const float4* c4 = reinterpret_cast<const float4*>(c + (size_t)k * DD);
        const float4 ca = c4[lane * 2];
        const float4 cb = c4[lane * 2 + 1];
        float dotv = xa.x * ca.x + xa.y * ca.y + xa.z * ca.z + xa.w * ca.w
                   + xb.x * cb.x + xb.y * cb.y + xb.z * cb.z + xb.w * cb.w;
        float cc = ca.x * ca.x + ca.y * ca.y + ca.z * ca.z + ca.w * ca.w
                 + cb.x * cb.x + cb.y * cb.y + cb.z * cb.z + cb.w * cb.w;
        float v = cc - 2.0f * dotv;   // ||x||^2 constant across k (argmin-invariant)
        #pragma unroll
        for (int off = 32; off > 0; off >>= 1) v += __shfl_xor(v, off, 64);
        if (v < bestd) { bestd = v; bestk = k; }   // strict < keeps first-min
    }
    if (lane == 0) {
        const int pos = atomicAdd(&counts[bestk], 1);
        rows[bestk * BB + pos] = row;
    }
}

// Fragment conventions (mfma_f32_16x16x32_bf16, lane l, k-group g=l>>4):
//   A: row = l&15, k = 8g+j     B: k = 8g+j, col = l&15
//   D: col = l&15, row = 4g+reg   [measured m89; k-permutation cancels A<->B]

// ---- encoder: e = relu(xc @ encW[k] + encB[k]), per-tile 16x128, K=512 ----
__global__ __launch_bounds__(256) void enc_k(const float* __restrict__ x,
                                             const float* __restrict__ c,
                                             const float* __restrict__ encW,
                                             const float* __restrict__ encB,
                                             const int* __restrict__ counts,
                                             const int* __restrict__ rows,
                                             float* __restrict__ e) {
    const int k = blockIdx.x >> 7;
    const int tile = blockIdx.x & (MAXT - 1);
    const int cnt = counts[k];
    const int base = tile * TM;
    if (base >= cnt) return;
    const int nrows = min(TM, cnt - base);

    __shared__ int4 Ah[16 * 64];      // 16 KB: A-hi frags, [kstep][lane]
    __shared__ int4 Al[16 * 64];      // 16 KB: A-lo frags
    __shared__ int rs_s[TM];

    const int tid = threadIdx.x;
    if (tid < TM) rs_s[tid] = (tid < nrows) ? rows[k * BB + base + tid] : -1;
    __syncthreads();

    const int l = tid & 63;
    const int r16 = l & 15;
    const int g = l >> 4;
    const int w = tid >> 6;

    // ---- stage A = bf16split(x[row] - c[k]) directly in fragment layout ----
    {
        const int grow = rs_s[r16];
        #pragma unroll
        for (int i = 0; i < 4; ++i) {
            const int s = w * 4 + i;              // kstep 0..15
            const int col = s * 32 + g * 8;
            float xc[8] = {0.f, 0.f, 0.f, 0.f, 0.f, 0.f, 0.f, 0.f};
            if (grow >= 0) {
                const float4 xa = *(const float4*)(x + (size_t)grow * DD + col);
                const float4 xb = *(const float4*)(x + (size_t)grow * DD + col + 4);
                const float4 ca = *(const float4*)(c + (size_t)k * DD + col);
                const float4 cb = *(const float4*)(c + (size_t)k * DD + col + 4);
                xc[0] = xa.x - ca.x; xc[1] = xa.y - ca.y;
                xc[2] = xa.z - ca.z; xc[3] = xa.w - ca.w;
                xc[4] = xb.x - cb.x; xc[5] = xb.y - cb.y;
                xc[6] = xb.z - cb.z; xc[7] = xb.w - cb.w;
            }
            uint hu[8], lu[8];
            #pragma unroll
            for (int j = 0; j < 8; ++j) {
                hu[j] = f2bf(xc[j]);
                lu[j] = f2bf(xc[j] - bf2f((ushort)hu[j]));
            }
            int4 H, L;
            H.x = (int)(hu[0] | (hu[1] << 16)); H.y = (int)(hu[2] | (hu[3] << 16));
            H.z = (int)(hu[4] | (hu[5] << 16)); H.w = (int)(hu[6] | (hu[7] << 16));
            L.x = (int)(lu[0] | (lu[1] << 16)); L.y = (int)(lu[2] | (lu[3] << 16));
            L.z = (int)(lu[4] | (lu[5] << 16)); L.w = (int)(lu[6] | (lu[7] << 16));
            Ah[s * 64 + l] = H;                   // lane-linear: conflict-free
            Al[s * 64 + l] = L;
        }
    }
    __syncthreads();

    // ---- MFMA main loop: wave w owns h-cols [32w, 32w+32) = 2 n-frags ----
    f4v acc0 = {0.f, 0.f, 0.f, 0.f};
    f4v acc1 = {0.f, 0.f, 0.f, 0.f};
    const float* W = encW + (size_t)k * DD * HH + w * 32 + r16;

    #pragma unroll 4
    for (int s = 0; s < 16; ++s) {
        const s8v ah = *(const s8v*)&Ah[s * 64 + l];
        const s8v al = *(const s8v*)&Al[s * 64 + l];
        const float* wp = W + (size_t)(s * 32 + g * 8) * HH;
        float b0[8], b1[8];
        #pragma unroll
        for (int j = 0; j < 8; ++j) {             // 16 indep loads: ILP
            b0[j] = wp[(size_t)j * HH];
            b1[j] = wp[(size_t)j * HH + 16];
        }
        const s8v bf0 = pack8(b0);
        const s8v bf1 = pack8(b1);
        acc0 = __builtin_amdgcn_mfma_f32_16x16x32_bf16(ah, bf0, acc0, 0, 0, 0);
        acc0 = __builtin_amdgcn_mfma_f32_16x16x32_bf16(al, bf0, acc0, 0, 0, 0);
        acc1 = __builtin_amdgcn_mfma_f32_16x16x32_bf16(ah, bf1, acc1, 0, 0, 0);
        acc1 = __builtin_amdgcn_mfma_f32_16x16x32_bf16(al, bf1, acc1, 0, 0, 0);
    }

    // ---- epilogue: bias + relu -> e[row][h] ----
    #pragma unroll
    for (int rr = 0; rr < 4; ++rr) {
        const int row = g * 4 + rr;
        const int grow = rs_s[row];
        if (grow >= 0) {
            const int h0 = w * 32 + r16;
            e[(size_t)grow * HH + h0]      = fmaxf(acc0[rr] + encB[k * HH + h0], 0.f);
            e[(size_t)grow * HH + h0 + 16] = fmaxf(acc1[rr] + encB[k * HH + h0 + 16], 0.f);
        }
    }
}

// ---- decoder: out = e @ decW[k] + decB[k], per-tile 16x512, K=128 ----
__global__ __launch_bounds__(256) void dec_k(const float* __restrict__ e,
                                             const float* __restrict__ decW,
                                             const float* __restrict__ decB,
                                             const int* __restrict__ counts,
                                             const int* __restrict__ rows,
                                             float* __restrict__ out) {
    const int k = blockIdx.x >> 7;
    const int tile = blockIdx.x & (MAXT - 1);
    const int cnt = counts[k];
    const int base = tile * TM;
    if (base >= cnt) return;
    const int nrows = min(TM, cnt - base);

    __shared__ int4 Ah[4 * 64];       // 4 KB
    __shared__ int4 Al[4 * 64];
    __shared__ int rs_s[TM];

    const int tid = threadIdx.x;
    if (tid < TM) rs_s[tid] = (tid < nrows) ? rows[k * BB + base + tid] : -1;
    __syncthreads();

    const int l = tid & 63;
    const int r16 = l & 15;
    const int g = l >> 4;
    const int w = tid >> 6;

    // ---- stage A = bf16split(e-tile) in fragment layout (1 slot/thread) ----
    {
        const int grow = rs_s[r16];
        const int s = w;                          // kstep 0..3
        const int col = s * 32 + g * 8;
        float ev[8] = {0.f, 0.f, 0.f, 0.f, 0.f, 0.f, 0.f, 0.f};
        if (grow >= 0) {
            const float4 ea = *(const float4*)(e + (size_t)grow * HH + col);
            const float4 eb = *(const float4*)(e + (size_t)grow * HH + col + 4);
            ev[0] = ea.x; ev[1] = ea.y; ev[2] = ea.z; ev[3] = ea.w;
            ev[4] = eb.x; ev[5] = eb.y; ev[6] = eb.z; ev[7] = eb.w;
        }
        uint hu[8], lu[8];
        #pragma unroll
        for (int j = 0; j < 8; ++j) {
            hu[j] = f2bf(ev[j]);
            lu[j] = f2bf(ev[j] - bf2f((ushort)hu[j]));
        }
        int4 H, L;
        H.x = (int)(hu[0] | (hu[1] << 16)); H.y = (int)(hu[2] | (hu[3] << 16));
        H.z = (int)(hu[4] | (hu[5] << 16)); H.w = (int)(hu[6] | (hu[7] << 16));
        L.x = (int)(lu[0] | (lu[1] << 16)); L.y = (int)(lu[2] | (lu[3] << 16));
        L.z = (int)(lu[4] | (lu[5] << 16)); L.w = (int)(lu[6] | (lu[7] << 16));
        Ah[s * 64 + l] = H;
        Al[s * 64 + l] = L;
    }
    __syncthreads();

    // ---- MFMA: wave w owns d-cols [128w, 128w+128) = 8 n-frags, 4 ksteps ----
    f4v acc[8];
    #pragma unroll
    for (int f = 0; f < 8; ++f) acc[f] = (f4v){0.f, 0.f, 0.f, 0.f};

    const float* W = decW + (size_t)k * HH * DD + w * 128 + r16;
    #pragma unroll
    for (int s = 0; s < 4; ++s) {
        const s8v ah = *(const s8v*)&Ah[s * 64 + l];
        const s8v al = *(const s8v*)&Al[s * 64 + l];
        const float* wp = W + (size_t)(s * 32 + g * 8) * DD;
        #pragma unroll
        for (int f = 0; f < 8; ++f) {             // 64 indep loads per kstep
            float b[8];
            #pragma unroll
            for (int j = 0; j < 8; ++j) b[j] = wp[(size_t)j * DD + f * 16];
            const s8v bf = pack8(b);
            acc[f] = __builtin_amdgcn_mfma_f32_16x16x32_bf16(ah, bf, acc[f], 0, 0, 0);
            acc[f] = __builtin_amdgcn_mfma_f32_16x16x32_bf16(al, bf, acc[f], 0, 0, 0);
        }
    }

    // ---- epilogue: + bias -> out[row][d] ----
    #pragma unroll
    for (int rr = 0; rr < 4; ++rr) {
        const int row = g * 4 + rr;
        const int grow = rs_s[row];
        if (grow >= 0) {
            #pragma unroll
            for (int f = 0; f < 8; ++f) {
                const int d = w * 128 + f * 16 + r16;
                out[(size_t)grow * DD + d] = acc[f][rr] + decB[k * DD + d];
            }
        }
    }
}

extern "C" void kernel_launch(void* const* d_in, const int* in_sizes, int n_in,
                              void* d_out, int out_size, void* d_ws, size_t ws_size,
                              hipStream_t stream) {
    const float* x       = (const float*)d_in[0];
    const float* centers = (const float*)d_in[1];
    const float* enc_W   = (const float*)d_in[2];
    const float* enc_b   = (const float*)d_in[3];
    const float* dec_W   = (const float*)d_in[4];
    const float* dec_b   = (const float*)d_in[5];
    float* out = (float*)d_out;

    // ws: [0,64) counts; [4096, +128K) row lists; then e (B*H f32, 1 MB)
    int*   counts = (int*)d_ws;
    int*   rows   = (int*)((char*)d_ws + 4096);
    float* e      = (float*)((char*)d_ws + 4096 + KK * BB * sizeof(int));

    hipMemsetAsync(counts, 0, KK * sizeof(int), stream);
    assign_k<<<BB / 4, 256, 0, stream>>>(x, centers, counts, rows);
    enc_k<<<KK * MAXT, 256, 0, stream>>>(x, centers, enc_W, enc_b,
                                         counts, rows, e);
    dec_k<<<KK * MAXT, 256, 0, stream>>>(e, dec_W, dec_b,
                                         counts, rows, out);
}

// Round 4
// 35.404 us; speedup vs baseline: 6.1534x; 2.1664x over previous
//
#include <hip/hip_runtime.h>

// TensorizedAutoencoder: B=2048, D=512, H=128, K=16, f32 in/out.
// R4: 2 kernels. assign_k writes idx[] (no atomics, no memset). ae_k (143
// blocks x 512 thr): every block redundantly buckets (LDS hist + wave scan of
// idx, ~1-2us, parallel), finds its (cluster,tile) 16-row slice, then fused
// enc MFMA -> e in LDS -> dec MFMA. A-operands split hi+lo bf16 (exact-ish);
// weights bf16 via v_cvt_pk_bf16_f32. D-layout per m89: col=l&15, row=4g+reg.

#define BB 2048
#define DD 512
#define HH 128
#define KK 16
#define MAXTILES 143   // max sum of ceil(cnt_k/16) = 128 + 15

typedef float f4v __attribute__((ext_vector_type(4)));
typedef short s8v __attribute__((ext_vector_type(8)));

union U4 { uint4 u; int4 i; s8v v; };

__device__ inline uint pk2(float a, float b) {   // {bf16(a), bf16(b)} packed
    uint r;
    asm("v_cvt_pk_bf16_f32 %0, %1, %2" : "=v"(r) : "v"(a), "v"(b));
    return r;
}
__device__ inline void split2(float a, float b, uint& hi, uint& lo) {
    hi = pk2(a, b);
    const float ha = __uint_as_float(hi << 16);
    const float hb = __uint_as_float(hi & 0xffff0000u);
    lo = pk2(a - ha, b - hb);                    // residual: split self-corrects
}

__global__ __launch_bounds__(256) void assign_k(const float* __restrict__ x,
                                                const float* __restrict__ c,
                                                int* __restrict__ idx) {
    const int lane = threadIdx.x & 63;
    const int row = (blockIdx.x << 2) + (threadIdx.x >> 6);
    if (row >= BB) return;

    const float4* x4 = reinterpret_cast<const float4*>(x + (size_t)row * DD);
    const float4 xa = x4[lane * 2];
    const float4 xb = x4[lane * 2 + 1];

    float bestd = 3.4e38f;
    int bestk = 0;
    for (int k = 0; k < KK; ++k) {
        const float4* c4 = reinterpret_cast<const float4*>(c + (size_t)k * DD);
        const float4 ca = c4[lane * 2];
        const float4 cb = c4[lane * 2 + 1];
        float dotv = xa.x * ca.x + xa.y * ca.y + xa.z * ca.z + xa.w * ca.w
                   + xb.x * cb.x + xb.y * cb.y + xb.z * cb.z + xb.w * cb.w;
        float cc = ca.x * ca.x + ca.y * ca.y + ca.z * ca.z + ca.w * ca.w
                 + cb.x * cb.x + cb.y * cb.y + cb.z * cb.z + cb.w * cb.w;
        float v = cc - 2.0f * dotv;   // ||x||^2 constant across k (argmin-invariant)
        #pragma unroll
        for (int off = 32; off > 0; off >>= 1) v += __shfl_xor(v, off, 64);
        if (v < bestd) { bestd = v; bestk = k; }   // strict < keeps first-min
    }
    if (lane == 0) idx[row] = bestk;
}

// Fragment conventions (mfma_f32_16x16x32_bf16, lane l, g=l>>4):
//   A: row=l&15, k=8g+j   B: k=8g+j, col=l&15   D: col=l&15, row=4g+reg [m89]
__global__ __launch_bounds__(512) void ae_k(const float* __restrict__ x,
                                            const float* __restrict__ c,
                                            const float* __restrict__ encW,
                                            const float* __restrict__ encB,
                                            const float* __restrict__ decW,
                                            const float* __restrict__ decB,
                                            const int* __restrict__ idx,
                                            float* __restrict__ out) {
    __shared__ int4 frag[2048];          // 32 KB multi-use: hist / enc A / dec A
    __shared__ float e_s[16][132];       // 8.25 KB, stride 132: 2-way on enc write
    __shared__ int rs_s[16];
    __shared__ ushort cnt_s[KK];
    __shared__ ushort tb_s[KK + 1];

    const int tid = threadIdx.x;
    const int b = blockIdx.x;
    const int w = tid >> 6, l = tid & 63;
    const int r16 = l & 15, g = l >> 4;

    // ---- phase 0: redundant per-block bucket scan (deterministic) ----
    ushort (*hist)[KK] = reinterpret_cast<ushort (*)[KK]>(frag);  // [512][16]

    const int4 my = *reinterpret_cast<const int4*>(idx + tid * 4);
    if (tid < 16) rs_s[tid] = -1;
    {
        ushort h[KK];
        #pragma unroll
        for (int k = 0; k < KK; ++k) h[k] = 0;
        h[my.x]++; h[my.y]++; h[my.z]++; h[my.w]++;
        #pragma unroll
        for (int k = 0; k < KK; ++k) hist[tid][k] = h[k];
    }
    __syncthreads();

    // wave w scans clusters 2w, 2w+1 over thread-order (lane l owns t=8l..8l+7)
    #pragma unroll
    for (int kk = 0; kk < 2; ++kk) {
        const int k = w * 2 + kk;
        int v[8], s = 0;
        #pragma unroll
        for (int i = 0; i < 8; ++i) { v[i] = hist[l * 8 + i][k]; s += v[i]; }
        int sc = s;
        #pragma unroll
        for (int off = 1; off < 64; off <<= 1) {
            const int u = __shfl_up(sc, off, 64);
            if (l >= off) sc += u;
        }
        int e = sc - s;                  // exclusive start for t = 8l
        #pragma unroll
        for (int i = 0; i < 8; ++i) { hist[l * 8 + i][k] = (ushort)e; e += v[i]; }
        if (l == 63) cnt_s[k] = (ushort)sc;
    }
    __syncthreads();
    if (tid == 0) {
        int ta = 0;
        for (int k = 0; k < KK; ++k) { tb_s[k] = (ushort)ta; ta += (cnt_s[k] + 15) >> 4; }
        tb_s[KK] = (ushort)ta;
    }
    __syncthreads();
    if (b >= (int)tb_s[KK]) return;      // uniform exit
    int km = 0;
    #pragma unroll
    for (int kk = 1; kk < KK; ++kk) if (b >= (int)tb_s[kk]) km = kk;
    const int base16 = (b - tb_s[km]) * 16;

    {   // scatter: my rows of cluster km whose rank lands in this tile
        int rank = hist[tid][km];
        const int rv[4] = {my.x, my.y, my.z, my.w};
        #pragma unroll
        for (int i = 0; i < 4; ++i) {
            if (rv[i] == km) {
                if (rank >= base16 && rank < base16 + 16)
                    rs_s[rank - base16] = tid * 4 + i;
                rank++;
            }
        }
    }
    __syncthreads();

    // ---- stage enc A = bf16split(x[row]-c[km]) in frag layout (2 slots/thr) ----
    int4* Ah = frag;                     // [16 ksteps][64 lanes]
    int4* Al = frag + 1024;
    {
        const int grow = rs_s[r16];
        const int s0 = tid >> 6;
        #pragma unroll
        for (int ss = 0; ss < 2; ++ss) {
            const int s = s0 + ss * 8;
            const int c0 = s * 32 + g * 8;
            float xv[8] = {0.f, 0.f, 0.f, 0.f, 0.f, 0.f, 0.f, 0.f};
            if (grow >= 0) {
                const float4 xa = *(const float4*)(x + (size_t)grow * DD + c0);
                const float4 xb = *(const float4*)(x + (size_t)grow * DD + c0 + 4);
                const float4 ca = *(const float4*)(c + (size_t)km * DD + c0);
                const float4 cb = *(const float4*)(c + (size_t)km * DD + c0 + 4);
                xv[0] = xa.x - ca.x; xv[1] = xa.y - ca.y;
                xv[2] = xa.z - ca.z; xv[3] = xa.w - ca.w;
                xv[4] = xb.x - cb.x; xv[5] = xb.y - cb.y;
                xv[6] = xb.z - cb.z; xv[7] = xb.w - cb.w;
            }
            U4 H, L;
            split2(xv[0], xv[1], H.u.x, L.u.x);
            split2(xv[2], xv[3], H.u.y, L.u.y);
            split2(xv[4], xv[5], H.u.z, L.u.z);
            split2(xv[6], xv[7], H.u.w, L.u.w);
            Ah[s * 64 + l] = H.i;        // lane-linear: conflict-free
            Al[s * 64 + l] = L.i;
        }
    }
    __syncthreads();

    // ---- enc MFMA: wave w owns h-cols [16w,16w+16), K=512 = 16 ksteps ----
    f4v aH = {0.f, 0.f, 0.f, 0.f}, aL = {0.f, 0.f, 0.f, 0.f};
    {
        const float* Wp = encW + (size_t)km * DD * HH + w * 16 + r16;
        #pragma unroll 4
        for (int s = 0; s < 16; ++s) {
            U4 ah, al;
            ah.i = Ah[s * 64 + l];
            al.i = Al[s * 64 + l];
            const float* wp = Wp + (size_t)(s * 32 + g * 8) * HH;
            float bl[8];
            #pragma unroll
            for (int j = 0; j < 8; ++j) bl[j] = wp[(size_t)j * HH];
            U4 bf;
            bf.u = make_uint4(pk2(bl[0], bl[1]), pk2(bl[2], bl[3]),
                              pk2(bl[4], bl[5]), pk2(bl[6], bl[7]));
            aH = __builtin_amdgcn_mfma_f32_16x16x32_bf16(ah.v, bf.v, aH, 0, 0, 0);
            aL = __builtin_amdgcn_mfma_f32_16x16x32_bf16(al.v, bf.v, aL, 0, 0, 0);
        }
        const float bias = encB[km * HH + w * 16 + r16];
        #pragma unroll
        for (int rr = 0; rr < 4; ++rr)
            e_s[g * 4 + rr][w * 16 + r16] = fmaxf(aH[rr] + aL[rr] + bias, 0.f);
    }
    __syncthreads();

    // ---- stage dec A = bf16split(e) in frag layout (256 threads, 1 slot) ----
    int4* Dh = frag;                     // [4 ksteps][64 lanes] (reuse enc bufs)
    int4* Dl = frag + 256;
    if (tid < 256) {
        const int s = tid >> 6, ll = tid & 63;
        const int c0 = s * 32 + (ll >> 4) * 8;
        const float4 ea = *(const float4*)&e_s[ll & 15][c0];
        const float4 eb = *(const float4*)&e_s[ll & 15][c0 + 4];
        U4 H, L;
        split2(ea.x, ea.y, H.u.x, L.u.x);
        split2(ea.z, ea.w, H.u.y, L.u.y);
        split2(eb.x, eb.y, H.u.z, L.u.z);
        split2(eb.z, eb.w, H.u.w, L.u.w);
        Dh[s * 64 + ll] = H.i;
        Dl[s * 64 + ll] = L.i;
    }
    __syncthreads();

    // ---- dec MFMA: wave w owns d-cols [64w,64w+64) = 4 frags, K=128 ----
    f4v dH[4], dL[4];
    #pragma unroll
    for (int f = 0; f < 4; ++f) { dH[f] = (f4v){0.f,0.f,0.f,0.f}; dL[f] = (f4v){0.f,0.f,0.f,0.f}; }
    {
        const float* Vp = decW + (size_t)km * HH * DD + w * 64 + r16;
        #pragma unroll
        for (int s = 0; s < 4; ++s) {
            U4 ah, al;
            ah.i = Dh[s * 64 + l];
            al.i = Dl[s * 64 + l];
            const float* vp = Vp + (size_t)(s * 32 + g * 8) * DD;
            #pragma unroll
            for (int f = 0; f < 4; ++f) {
                float bl[8];
                #pragma unroll
                for (int j = 0; j < 8; ++j) bl[j] = vp[(size_t)j * DD + f * 16];
                U4 bf;
                bf.u = make_uint4(pk2(bl[0], bl[1]), pk2(bl[2], bl[3]),
                                  pk2(bl[4], bl[5]), pk2(bl[6], bl[7]));
                dH[f] = __builtin_amdgcn_mfma_f32_16x16x32_bf16(ah.v, bf.v, dH[f], 0, 0, 0);
                dL[f] = __builtin_amdgcn_mfma_f32_16x16x32_bf16(al.v, bf.v, dL[f], 0, 0, 0);
            }
        }
    }
    // ---- epilogue: + bias -> out ----
    #pragma unroll
    for (int f = 0; f < 4; ++f) {
        const int d = w * 64 + f * 16 + r16;
        const float db = decB[km * DD + d];
        #pragma unroll
        for (int rr = 0; rr < 4; ++rr) {
            const int grow = rs_s[g * 4 + rr];
            if (grow >= 0)
                out[(size_t)grow * DD + d] = dH[f][rr] + dL[f][rr] + db;
        }
    }
}

extern "C" void kernel_launch(void* const* d_in, const int* in_sizes, int n_in,
                              void* d_out, int out_size, void* d_ws, size_t ws_size,
                              hipStream_t stream) {
    const float* x       = (const float*)d_in[0];
    const float* centers = (const float*)d_in[1];
    const float* enc_W   = (const float*)d_in[2];
    const float* enc_b   = (const float*)d_in[3];
    const float* dec_W   = (const float*)d_in[4];
    const float* dec_b   = (const float*)d_in[5];
    float* out = (float*)d_out;

    int* idx = (int*)d_ws;               // 2048 ints, rewritten every call

    assign_k<<<BB / 4, 256, 0, stream>>>(x, centers, idx);
    ae_k<<<MAXTILES, 512, 0, stream>>>(x, centers, enc_W, enc_b, dec_W, dec_b,
                                       idx, out);
}